// Round 5
// baseline (176.441 us; speedup 1.0000x reference)
//
#include <hip/hip_runtime.h>
#include <hip/hip_bf16.h>
#include <stdint.h>

typedef __bf16 bf16;
typedef __bf16 bf16x8 __attribute__((ext_vector_type(8)));
typedef __bf16 bf16x4 __attribute__((ext_vector_type(4)));
typedef float  f32x4  __attribute__((ext_vector_type(4)));
typedef unsigned int u32;

typedef __attribute__((address_space(1))) u32 gu32;
typedef __attribute__((address_space(3))) u32 lu32;

__device__ __forceinline__ void gld_lds16(const void* g, void* l) {
  __builtin_amdgcn_global_load_lds((gu32*)(uintptr_t)g, (lu32*)(u32)(uintptr_t)l, 16, 0, 0);
}

__device__ __forceinline__ f32x4 mfma_bf16_16x16x32(bf16x8 a, bf16x8 b, f32x4 c) {
  return __builtin_amdgcn_mfma_f32_16x16x32_bf16(a, b, c, 0, 0, 0);
}

#define LGKM0 do { asm volatile("s_waitcnt lgkmcnt(0)" ::: "memory"); \
                   __builtin_amdgcn_sched_barrier(0); } while (0)
#define VMC0  do { asm volatile("s_waitcnt vmcnt(0)" ::: "memory"); } while (0)
#define BAR __builtin_amdgcn_s_barrier()
#define PRIO1 __builtin_amdgcn_s_setprio(1)
#define PRIO0 __builtin_amdgcn_s_setprio(0)

// ---------------- transpose w [512][1536] f32 -> wT [1536][512] bf16 ----------------
__global__ __launch_bounds__(256) void k_prep_w(const float* __restrict__ w,
                                                bf16* __restrict__ wT) {
  int idx = blockIdx.x * 256 + threadIdx.x;
  int n = idx >> 9;
  int k = idx & 511;
  wT[idx] = (bf16)w[k * 1536 + n];
}

template <int MH, int NH>
__device__ __forceinline__ void mm(f32x4 (&acc)[8][4],
                                   const bf16x8 (&a)[4][2],
                                   const bf16x8 (&b)[2][2]) {
#pragma unroll
  for (int fm = 0; fm < 4; ++fm)
#pragma unroll
    for (int fn = 0; fn < 2; ++fn)
#pragma unroll
      for (int ks = 0; ks < 2; ++ks)
        acc[MH * 4 + fm][NH * 2 + fn] =
            mfma_bf16_16x16x32(a[fm][ks], b[fn][ks], acc[MH * 4 + fm][NH * 2 + fn]);
}

// ---------------- QKV GEMM with FUSED f32->bf16 cast of x ----------------
// A = x [32768][512] f32, reg-staged with DISTANCE-2 pipeline:
//   aload(ktl t+3) at step t P2/P3 (after own awrite) -> awrite at step t+1 P2/P3
//   -> consumed at step t+3.  Issue->write = 4 phases (covers HBM latency).
// B = wT bf16 via global_load_lds issued at P1 (before aloads); its landing is
// vmcnt-subsumed by the next step's awrite wait.  Last B tile: VMC0 at t=6.
__global__ __launch_bounds__(512, 2) void k_qkv_gemm(
    const float* __restrict__ X, const bf16* __restrict__ Bt,
    const float* __restrict__ qg, const float* __restrict__ qbeta,
    const float* __restrict__ kg, const float* __restrict__ kbeta,
    bf16* __restrict__ qh, bf16* __restrict__ kt, bf16* __restrict__ vt)
{
  extern __shared__ bf16 lds[];
  const int tid = threadIdx.x;
  const int lane = tid & 63;
  const int w = tid >> 6;        // 0..7
  const int wm = w >> 2;         // 0..1
  const int wn = w & 3;          // 0..3

  // XCD-bijective swizzle: 768 blocks = 8 XCDs x 96; 6 consecutive share tm.
  const int wg = blockIdx.x;
  const int swz = (wg & 7) * 96 + (wg >> 3);
  const int tn = swz % 6;
  const int tm = swz / 6;

  // ---- A reg-staging geometry ----
  const int vrl = tid >> 1;            // 0..255
  const int kh  = tid & 1;             // which 32-float half of the 64-k row
  const int aslot = vrl >> 7;          // waves 0-3 -> slot0, waves 4-7 -> slot1
  const int avr = vrl & 127;           // row within slot
  const int agrow = tm * 256 + ((avr >> 6) * 128) + aslot * 64 + (avr & 63);
  const float* aptr = X + (size_t)agrow * 512 + kh * 32;

  float4 L[8];
  auto aload = [&](int ktl) {
    const float4* p = (const float4*)(aptr + ktl * 64);
#pragma unroll
    for (int i = 0; i < 8; ++i) L[i] = p[i];
  };
  auto awrite = [&](int buf) {
    char* base = (char*)lds + (buf * 2 + aslot) * 16384 + avr * 128;
#pragma unroll
    for (int i = 0; i < 4; ++i) {
      bf16x8 v;
      float4 a = L[2 * i], b = L[2 * i + 1];
      v[0] = (bf16)a.x; v[1] = (bf16)a.y; v[2] = (bf16)a.z; v[3] = (bf16)a.w;
      v[4] = (bf16)b.x; v[5] = (bf16)b.y; v[6] = (bf16)b.z; v[7] = (bf16)b.w;
      *(bf16x8*)(base + (((kh * 4 + i) ^ (avr & 7)) * 16)) = v;
    }
  };

  const int srow8 = lane >> 3;
  const int sblkX = lane & 7;
  auto stB = [&](int buf, int slot, int ktl) {
#pragma unroll
    for (int ii = 0; ii < 2; ++ii) {
      int vr = ii * 64 + w * 8 + srow8;
      int grow = tn * 256 + (vr >> 5) * 64 + slot * 32 + (vr & 31);
      int gk = ktl * 64 + ((sblkX ^ (vr & 7)) * 8);
      gld_lds16(Bt + (size_t)grow * 512 + gk,
                (char*)lds + 65536 + (buf * 2 + slot) * 16384 + ii * 8192 + w * 1024);
    }
  };
  auto rdA = [&](int buf, int mh, bf16x8 (&fr)[4][2]) {
    const bf16* base = lds + (buf * 2 + mh) * 8192;
#pragma unroll
    for (int f = 0; f < 4; ++f) {
      int vr = wm * 64 + f * 16 + (lane & 15);
#pragma unroll
      for (int ks = 0; ks < 2; ++ks) {
        int pb = (ks * 4 + (lane >> 4)) ^ (vr & 7);
        fr[f][ks] = *(const bf16x8*)(base + vr * 64 + pb * 8);
      }
    }
  };
  auto rdB = [&](int buf, int nh, bf16x8 (&fr)[2][2]) {
    const bf16* base = lds + 32768 + (buf * 2 + nh) * 8192;
#pragma unroll
    for (int f = 0; f < 2; ++f) {
      int vr = wn * 32 + f * 16 + (lane & 15);
#pragma unroll
      for (int ks = 0; ks < 2; ++ks) {
        int pb = (ks * 4 + (lane >> 4)) ^ (vr & 7);
        fr[f][ks] = *(const bf16x8*)(base + vr * 64 + pb * 8);
      }
    }
  };

  bf16x8 afr[4][2];
  bf16x8 bfr0[2][2], bfr1[2][2];
  f32x4 acc[8][4];
  {
    f32x4 z = {0.f, 0.f, 0.f, 0.f};
#pragma unroll
    for (int m = 0; m < 8; ++m)
#pragma unroll
      for (int n = 0; n < 4; ++n) acc[m][n] = z;
  }

  // ---- prologue: B tiles 0,1; A ktl 0,1 written; ktl 2 held in L ----
  stB(0, 0, 0); stB(0, 1, 0); stB(1, 0, 1); stB(1, 1, 1);
  aload(0); awrite(0);
  aload(1); awrite(1);
  aload(2);                      // written at step 0 P2/P3 into buf 0
  VMC0;                          // B bufs 0,1 landed (A loads drained too)
  LGKM0;                         // publish A ds_writes
  BAR;

#pragma unroll
  for (int t = 0; t < 8; ++t) {
    const int d = t & 1;

    // ---- P0: read afr(A0), bfr0, bfr1
    rdA(d, 0, afr);
    rdB(d, 0, bfr0);
    rdB(d, 1, bfr1);
    BAR;
    LGKM0;
    PRIO1; mm<0, 0>(acc, afr, bfr0); PRIO0;
    BAR;

    // ---- P1: stage B for step t+2; MFMA <0,1>
    if (t <= 5) { stB(d, 0, t + 2); stB(d, 1, t + 2); }
    BAR;
    PRIO1; mm<0, 1>(acc, afr, bfr1); PRIO0;
    BAR;

    // ---- P2: slot0 waves: write ktl t+2 (loaded at t-1) into buf d, then load t+3;
    //          re-read afr <- A1; MFMA <1,0>
    if (t <= 5 && aslot == 0) awrite(d);
    if (t <= 4 && aslot == 0) aload(t + 3);
    rdA(d, 1, afr);
    BAR;
    LGKM0;
    PRIO1; mm<1, 0>(acc, afr, bfr0); PRIO0;
    BAR;

    // ---- P3: slot1 waves ditto; MFMA <1,1>; t=6: drain last B glds
    if (t <= 5 && aslot == 1) awrite(d);
    if (t <= 4 && aslot == 1) aload(t + 3);
    if (t == 6) VMC0;
    BAR;
    PRIO1; mm<1, 1>(acc, afr, bfr1); PRIO0;
    BAR;
  }

  // ---- epilogue: wave owns 128 rows x one 64-col head block ----
  const int colbase = tn * 256 + wn * 64;
  const int part = colbase >> 9;           // 0=q 1=k 2=v
  const int hcol = (colbase >> 6) & 7;     // head
  const int dlane = lane & 15;
  const int rsub = (lane >> 4) * 4;

  if (part == 2) {  // v: no LN, store transposed [bh][d][n]
#pragma unroll
    for (int m = 0; m < 8; ++m) {
      int rowg = tm * 256 + wm * 128 + m * 16 + rsub;
      int bb = rowg >> 12, n0 = rowg & 4095;
      size_t bh64 = (size_t)(bb * 8 + hcol) * 64;
#pragma unroll
      for (int fn = 0; fn < 4; ++fn) {
        bf16x4 pk;
#pragma unroll
        for (int r = 0; r < 4; ++r) pk[r] = (bf16)acc[m][fn][r];
        *(bf16x4*)(vt + (bh64 + fn * 16 + dlane) * 4096 + n0) = pk;
      }
    }
  } else {
    const float* gamma = (part == 0) ? qg : kg;
    const float* beta  = (part == 0) ? qbeta : kbeta;
    float g4[4], b4[4];
#pragma unroll
    for (int fn = 0; fn < 4; ++fn) {
      g4[fn] = gamma[fn * 16 + dlane];
      b4[fn] = beta[fn * 16 + dlane];
    }
#pragma unroll
    for (int m = 0; m < 8; ++m) {
      float mu[4], rs[4];
#pragma unroll
      for (int r = 0; r < 4; ++r) {
        float s  = acc[m][0][r] + acc[m][1][r] + acc[m][2][r] + acc[m][3][r];
        float s2 = acc[m][0][r] * acc[m][0][r] + acc[m][1][r] * acc[m][1][r]
                 + acc[m][2][r] * acc[m][2][r] + acc[m][3][r] * acc[m][3][r];
#pragma unroll
        for (int msk = 1; msk < 16; msk <<= 1) {
          s  += __shfl_xor(s, msk, 64);
          s2 += __shfl_xor(s2, msk, 64);
        }
        float mean = s * (1.0f / 64.0f);
        float var  = s2 * (1.0f / 64.0f) - mean * mean;
        mu[r] = mean;
        rs[r] = rsqrtf(var + 1e-5f);
      }
      int rowg = tm * 256 + wm * 128 + m * 16 + rsub;
      int bb = rowg >> 12, n0 = rowg & 4095;
      int bh = bb * 8 + hcol;
      if (part == 0) {  // q: [bh][n][d]
        bf16* dst = qh + ((size_t)bh * 4096 + n0) * 64;
#pragma unroll
        for (int r = 0; r < 4; ++r)
#pragma unroll
          for (int fn = 0; fn < 4; ++fn) {
            float xv = (acc[m][fn][r] - mu[r]) * rs[r] * g4[fn] + b4[fn];
            dst[(size_t)r * 64 + fn * 16 + dlane] = (bf16)xv;
          }
      } else {          // k: LN, store transposed [bh][d][n]
#pragma unroll
        for (int fn = 0; fn < 4; ++fn) {
          bf16x4 pk;
#pragma unroll
          for (int r = 0; r < 4; ++r)
            pk[r] = (bf16)((acc[m][fn][r] - mu[r]) * rs[r] * g4[fn] + b4[fn]);
          *(bf16x4*)(kt + ((size_t)bh * 64 + fn * 16 + dlane) * 4096 + n0) = pk;
        }
      }
    }
  }
}

// ---------------- dots^T = V^T K per (b,h), split-K=8, deterministic partials ----
__global__ __launch_bounds__(64) void k_dots(const bf16* __restrict__ vt,
                                             const bf16* __restrict__ kt,
                                             float* __restrict__ dTp) {
  __shared__ bf16 lA[64 * 64];
  __shared__ bf16 lB[64 * 64];
  const int lane = threadIdx.x;
  const int bh = blockIdx.y, ch = blockIdx.x;
  const bf16* Ab = vt + (size_t)bh * 64 * 4096 + ch * 512;
  const bf16* Bb = kt + (size_t)bh * 64 * 4096 + ch * 512;
  f32x4 acc[4][4] = {};
  const int srow = lane >> 3;
  const int sblk = (lane & 7) ^ srow;
  for (int ktile = 0; ktile < 8; ++ktile) {
    __syncthreads();
#pragma unroll
    for (int i = 0; i < 8; ++i) {
      int row = i * 8 + srow;
      gld_lds16(Ab + (size_t)row * 4096 + ktile * 64 + sblk * 8, (char*)lA + i * 1024);
      gld_lds16(Bb + (size_t)row * 4096 + ktile * 64 + sblk * 8, (char*)lB + i * 1024);
    }
    __syncthreads();
#pragma unroll
    for (int ks = 0; ks < 2; ++ks) {
      bf16x8 af[4], bq[4];
#pragma unroll
      for (int f = 0; f < 4; ++f) {
        int row = f * 16 + (lane & 15);
        int sb = (ks * 4 + (lane >> 4)) ^ (row & 7);
        af[f] = *(const bf16x8*)(lA + row * 64 + sb * 8);
        bq[f] = *(const bf16x8*)(lB + row * 64 + sb * 8);
      }
#pragma unroll
      for (int fm = 0; fm < 4; ++fm)
#pragma unroll
        for (int fn = 0; fn < 4; ++fn)
          acc[fm][fn] = mfma_bf16_16x16x32(af[fm], bq[fn], acc[fm][fn]);
    }
  }
  float* outp = dTp + (size_t)ch * 262144 + (size_t)bh * 4096;
#pragma unroll
  for (int fm = 0; fm < 4; ++fm)
#pragma unroll
    for (int fn = 0; fn < 4; ++fn)
#pragma unroll
      for (int r = 0; r < 4; ++r) {
        int e = fm * 16 + (lane >> 4) * 4 + r;
        int dd = fn * 16 + (lane & 15);
        outp[e * 64 + dd] = acc[fm][fn][r];
      }
}

// ---------------- reduce split-K partials, cast to bf16 ----------------
__global__ __launch_bounds__(256) void k_cvt_dt(const float* __restrict__ dTp,
                                                bf16* __restrict__ dTb) {
  int i = blockIdx.x * 256 + threadIdx.x;
  float s = 0.f;
#pragma unroll
  for (int c = 0; c < 8; ++c) s += dTp[(size_t)c * 262144 + i];
  dTb[i] = (bf16)s;
}

// ---------------- out = (Q @ dots) / n ----------------
__global__ __launch_bounds__(256) void k_out(const bf16* __restrict__ qh,
                                             const bf16* __restrict__ dTb,
                                             float* __restrict__ out) {
  __shared__ bf16 lA[128 * 64];
  const int tid = threadIdx.x, lane = tid & 63, w = tid >> 6;
  const int wm = w >> 1, wn = w & 1;
  const int bh = blockIdx.y, mt = blockIdx.x;
  const int bb = bh >> 3, h = bh & 7;
  const bf16* Ab = qh + (size_t)bh * 4096 * 64 + (size_t)mt * 128 * 64;
  const int srow = lane >> 3, sblk = (lane & 7) ^ srow;
#pragma unroll
  for (int i = 0; i < 4; ++i) {
    int slot = w * 4 + i;
    int row = slot * 8 + srow;
    gld_lds16(Ab + (size_t)row * 64 + sblk * 8, (char*)lA + slot * 1024);
  }
  __syncthreads();
  const bf16* Bb = dTb + (size_t)bh * 4096;
  f32x4 acc[4][2] = {};
#pragma unroll
  for (int ks = 0; ks < 2; ++ks) {
    bf16x8 af[4], bq[2];
#pragma unroll
    for (int f = 0; f < 4; ++f) {
      int row = wm * 64 + f * 16 + (lane & 15);
      int sb = (ks * 4 + (lane >> 4)) ^ (row & 7);
      af[f] = *(const bf16x8*)(lA + row * 64 + sb * 8);
    }
#pragma unroll
    for (int fn = 0; fn < 2; ++fn) {
      int e = wn * 32 + fn * 16 + (lane & 15);
      bq[fn] = *(const bf16x8*)(Bb + e * 64 + ks * 32 + (lane >> 4) * 8);
    }
#pragma unroll
    for (int fm = 0; fm < 4; ++fm)
#pragma unroll
      for (int fn = 0; fn < 2; ++fn)
        acc[fm][fn] = mfma_bf16_16x16x32(af[fm], bq[fn], acc[fm][fn]);
  }
#pragma unroll
  for (int fm = 0; fm < 4; ++fm)
#pragma unroll
    for (int fn = 0; fn < 2; ++fn)
#pragma unroll
      for (int r = 0; r < 4; ++r) {
        int n = mt * 128 + wm * 64 + fm * 16 + (lane >> 4) * 4 + r;
        int e = wn * 32 + fn * 16 + (lane & 15);
        out[((size_t)bb * 4096 + n) * 512 + h * 64 + e] = acc[fm][fn][r] * (1.0f / 4096.0f);
      }
}

extern "C" void kernel_launch(void* const* d_in, const int* in_sizes, int n_in,
                              void* d_out, int out_size, void* d_ws, size_t ws_size,
                              hipStream_t stream) {
  const float* x  = (const float*)d_in[0];
  const float* wq = (const float*)d_in[1];
  const float* qg = (const float*)d_in[2];
  const float* qb = (const float*)d_in[3];
  const float* kg = (const float*)d_in[4];
  const float* kb = (const float*)d_in[5];
  float* out = (float*)d_out;
  char* ws = (char*)d_ws;

  bf16* wT  = (bf16*)(ws);                          // 1.5 MB [1536][512]
  bf16* qh  = (bf16*)(ws + ((size_t)2 << 20));      // 32 MB  [64][4096][64]
  bf16* kt  = (bf16*)(ws + ((size_t)34 << 20));     // 32 MB  [64][64][4096]
  bf16* vt  = (bf16*)(ws + ((size_t)66 << 20));     // 32 MB  [64][64][4096]
  float* dTp = (float*)(ws + ((size_t)98 << 20));   // 8 MB
  bf16* dTb  = (bf16*)(ws + ((size_t)107 << 20));   // 0.5 MB

  k_prep_w<<<3072, 256, 0, stream>>>(wq, wT);
  k_qkv_gemm<<<768, 512, 131072, stream>>>(x, wT, qg, qb, kg, kb, qh, kt, vt);
  k_dots<<<dim3(8, 64), 64, 0, stream>>>(vt, kt, dTp);
  k_cvt_dt<<<1024, 256, 0, stream>>>(dTp, dTb);
  k_out<<<dim3(32, 64), 256, 0, stream>>>(qh, dTb, out);
}

// Round 6
// 134.943 us; speedup vs baseline: 1.3075x; 1.3075x over previous
//
#include <hip/hip_runtime.h>
#include <hip/hip_bf16.h>
#include <stdint.h>

typedef __bf16 bf16;
typedef __bf16 bf16x8 __attribute__((ext_vector_type(8)));
typedef __bf16 bf16x4 __attribute__((ext_vector_type(4)));
typedef float  f32x4  __attribute__((ext_vector_type(4)));
typedef unsigned int u32;

typedef __attribute__((address_space(1))) u32 gu32;
typedef __attribute__((address_space(3))) u32 lu32;

__device__ __forceinline__ void gld_lds16(const void* g, void* l) {
  __builtin_amdgcn_global_load_lds((gu32*)(uintptr_t)g, (lu32*)(u32)(uintptr_t)l, 16, 0, 0);
}

__device__ __forceinline__ f32x4 mfma_bf16_16x16x32(bf16x8 a, bf16x8 b, f32x4 c) {
  return __builtin_amdgcn_mfma_f32_16x16x32_bf16(a, b, c, 0, 0, 0);
}

#define LGKM0 do { asm volatile("s_waitcnt lgkmcnt(0)" ::: "memory"); \
                   __builtin_amdgcn_sched_barrier(0); } while (0)
#define VMC(n) do { asm volatile("s_waitcnt vmcnt(" #n ")" ::: "memory"); } while (0)
#define BAR __builtin_amdgcn_s_barrier()
#define PRIO1 __builtin_amdgcn_s_setprio(1)
#define PRIO0 __builtin_amdgcn_s_setprio(0)

// ---------------- transpose w [512][1536] f32 -> wT [1536][512] bf16 ----------------
__global__ __launch_bounds__(256) void k_prep_w(const float* __restrict__ w,
                                                bf16* __restrict__ wT) {
  int idx = blockIdx.x * 256 + threadIdx.x;
  int n = idx >> 9;
  int k = idx & 511;
  wT[idx] = (bf16)w[k * 1536 + n];
}

template <int MH, int NH>
__device__ __forceinline__ void mm(f32x4 (&acc)[8][4],
                                   const bf16x8 (&a)[4][2],
                                   const bf16x8 (&b)[2][2]) {
#pragma unroll
  for (int fm = 0; fm < 4; ++fm)
#pragma unroll
    for (int fn = 0; fn < 2; ++fn)
#pragma unroll
      for (int ks = 0; ks < 2; ++ks)
        acc[MH * 4 + fm][NH * 2 + fn] =
            mfma_bf16_16x16x32(a[fm][ks], b[fn][ks], acc[MH * 4 + fm][NH * 2 + fn]);
}

// ---------------- QKV GEMM, fused f32->bf16 cast, gld_lds-ONLY staging ----------
// A = x f32 staged RAW via global_load_lds into a single-buffered 2-slot region
// (64 KB); fragments read as f32 pairs and converted to bf16 in registers.
// B = wT bf16, double-buffered via global_load_lds (R2-identical).
// No ds_write anywhere -> no gld_lds/ds_write alias serialization (R4/R5 bug).
// All counted vmcnt are immediately followed by a barrier (cross-wave publish).
__global__ __launch_bounds__(512, 2) void k_qkv_gemm(
    const float* __restrict__ X, const bf16* __restrict__ Bt,
    const float* __restrict__ qg, const float* __restrict__ qbeta,
    const float* __restrict__ kg, const float* __restrict__ kbeta,
    bf16* __restrict__ qh, bf16* __restrict__ kt, bf16* __restrict__ vt)
{
  extern __shared__ bf16 lds[];   // bytes [0,65536): A f32 slots; [65536,131072): B
  const int tid = threadIdx.x;
  const int lane = tid & 63;
  const int w = tid >> 6;        // 0..7
  const int wm = w >> 2;         // 0..1
  const int wn = w & 3;          // 0..3

  // XCD-bijective swizzle: 768 = 8 x 96; 6 consecutive per XCD share tm.
  const int wg = blockIdx.x;
  const int swz = (wg & 7) * 96 + (wg >> 3);
  const int tn = swz % 6;
  const int tm = swz / 6;

  // ---- A staging: raw f32, 16B granules, source pre-swizzled ----
  // slot s holds tile rows {(vr>>6)*128 + s*64 + (vr&63)}, vr in [0,128);
  // LDS row vr at byte s*32768 + vr*256; phys 16B-block p holds source block
  // p ^ (vr&7)  (16 blocks of 4 floats per row).
  auto stAf = [&](int slot, int ktl) {
#pragma unroll
    for (int ii = 0; ii < 4; ++ii) {
      int vr = ii * 32 + w * 4 + (lane >> 4);
      int grow = tm * 256 + (vr >> 6) * 128 + slot * 64 + (vr & 63);
      int gk = ktl * 64 + (((lane & 15) ^ (vr & 7)) * 4);
      gld_lds16(X + (size_t)grow * 512 + gk,
                (char*)lds + slot * 32768 + ii * 8192 + w * 1024);
    }
  };
  // read f32 fragment + convert to bf16 in registers
  auto rdAf = [&](int mh, bf16x8 (&fr)[4][2]) {
    const char* base = (const char*)lds + mh * 32768;
#pragma unroll
    for (int f = 0; f < 4; ++f) {
      int vr = wm * 64 + f * 16 + (lane & 15);
#pragma unroll
      for (int ks = 0; ks < 2; ++ks) {
        int j0 = ks * 8 + (lane >> 4) * 2;
        f32x4 lo = *(const f32x4*)(base + vr * 256 + ((j0 ^ (vr & 7)) * 16));
        f32x4 hi = *(const f32x4*)(base + vr * 256 + (((j0 + 1) ^ (vr & 7)) * 16));
        bf16x8 v;
        v[0] = (bf16)lo[0]; v[1] = (bf16)lo[1]; v[2] = (bf16)lo[2]; v[3] = (bf16)lo[3];
        v[4] = (bf16)hi[0]; v[5] = (bf16)hi[1]; v[6] = (bf16)hi[2]; v[7] = (bf16)hi[3];
        fr[f][ks] = v;
      }
    }
  };

  const int srow8 = lane >> 3;
  const int sblkX = lane & 7;
  auto stB = [&](int buf, int slot, int ktl) {
#pragma unroll
    for (int ii = 0; ii < 2; ++ii) {
      int vr = ii * 64 + w * 8 + srow8;
      int grow = tn * 256 + (vr >> 5) * 64 + slot * 32 + (vr & 31);
      int gk = ktl * 64 + ((sblkX ^ (vr & 7)) * 8);
      gld_lds16(Bt + (size_t)grow * 512 + gk,
                (char*)lds + 65536 + (buf * 2 + slot) * 16384 + ii * 8192 + w * 1024);
    }
  };
  auto rdB = [&](int buf, int nh, bf16x8 (&fr)[2][2]) {
    const bf16* base = lds + 32768 + (buf * 2 + nh) * 8192;
#pragma unroll
    for (int f = 0; f < 2; ++f) {
      int vr = wn * 32 + f * 16 + (lane & 15);
#pragma unroll
      for (int ks = 0; ks < 2; ++ks) {
        int pb = (ks * 4 + (lane >> 4)) ^ (vr & 7);
        fr[f][ks] = *(const bf16x8*)(base + vr * 64 + pb * 8);
      }
    }
  };

  bf16x8 afr[4][2];
  bf16x8 bfr0[2][2], bfr1[2][2];
  f32x4 acc[8][4];
  {
    f32x4 z = {0.f, 0.f, 0.f, 0.f};
#pragma unroll
    for (int m = 0; m < 8; ++m)
#pragma unroll
      for (int n = 0; n < 4; ++n) acc[m][n] = z;
  }

  // ---- prologue: A(0) both slots; B tile0 full; B tile1 slot0 ----
  stB(0, 0, 0); stB(0, 1, 0); stB(1, 0, 1);
  stAf(0, 0); stAf(1, 0);
  VMC(0); BAR;

#pragma unroll
  for (int t = 0; t < 8; ++t) {
    const int d = t & 1;

    // ---- P0: read A0(f32)+B0; publish A1(t)/... via counted vmcnt+BAR
    rdAf(0, afr);
    rdB(d, 0, bfr0);
    if (t == 7) { VMC(0); } else if (t >= 1) { VMC(2); }  // A1(t) landed (B0(t+1) may fly)
    BAR;
    LGKM0;
    PRIO1; mm<0, 0>(acc, afr, bfr0); PRIO0;
    BAR;

    // ---- P1: read B1; stage A0(t+1) + B1(t+1)
    rdB(d, 1, bfr1);
    if (t < 7) { stAf(0, t + 1); stB(d ^ 1, 1, t + 1); }
    BAR;
    PRIO1; mm<0, 1>(acc, afr, bfr1); PRIO0;
    BAR;

    // ---- P2: read A1(f32) (published at P0's vmcnt+BAR)
    rdAf(1, afr);
    BAR;
    LGKM0;
    PRIO1; mm<1, 0>(acc, afr, bfr0); PRIO0;
    BAR;

    // ---- P3: stage A1(t+1) + B0(t+2); counted vmcnt then publishing BAR
    if (t < 7) stAf(1, t + 1);
    if (t < 6) stB(d, 0, t + 2);
    BAR;
    PRIO1; mm<1, 1>(acc, afr, bfr1); PRIO0;
    if (t < 6) { VMC(6); } else if (t == 6) { VMC(4); }   // A0(t+1)+B1(t+1) landed
    BAR;
  }

  // ---- epilogue: wave owns 128 rows x one 64-col head block ----
  const int colbase = tn * 256 + wn * 64;
  const int part = colbase >> 9;           // 0=q 1=k 2=v
  const int hcol = (colbase >> 6) & 7;     // head
  const int dlane = lane & 15;
  const int rsub = (lane >> 4) * 4;

  if (part == 2) {  // v: no LN, store transposed [bh][d][n]
#pragma unroll
    for (int m = 0; m < 8; ++m) {
      int rowg = tm * 256 + wm * 128 + m * 16 + rsub;
      int bb = rowg >> 12, n0 = rowg & 4095;
      size_t bh64 = (size_t)(bb * 8 + hcol) * 64;
#pragma unroll
      for (int fn = 0; fn < 4; ++fn) {
        bf16x4 pk;
#pragma unroll
        for (int r = 0; r < 4; ++r) pk[r] = (bf16)acc[m][fn][r];
        *(bf16x4*)(vt + (bh64 + fn * 16 + dlane) * 4096 + n0) = pk;
      }
    }
  } else {
    const float* gamma = (part == 0) ? qg : kg;
    const float* beta  = (part == 0) ? qbeta : kbeta;
    float g4[4], b4[4];
#pragma unroll
    for (int fn = 0; fn < 4; ++fn) {
      g4[fn] = gamma[fn * 16 + dlane];
      b4[fn] = beta[fn * 16 + dlane];
    }
#pragma unroll
    for (int m = 0; m < 8; ++m) {
      float mu[4], rs[4];
#pragma unroll
      for (int r = 0; r < 4; ++r) {
        float s  = acc[m][0][r] + acc[m][1][r] + acc[m][2][r] + acc[m][3][r];
        float s2 = acc[m][0][r] * acc[m][0][r] + acc[m][1][r] * acc[m][1][r]
                 + acc[m][2][r] * acc[m][2][r] + acc[m][3][r] * acc[m][3][r];
#pragma unroll
        for (int msk = 1; msk < 16; msk <<= 1) {
          s  += __shfl_xor(s, msk, 64);
          s2 += __shfl_xor(s2, msk, 64);
        }
        float mean = s * (1.0f / 64.0f);
        float var  = s2 * (1.0f / 64.0f) - mean * mean;
        mu[r] = mean;
        rs[r] = rsqrtf(var + 1e-5f);
      }
      int rowg = tm * 256 + wm * 128 + m * 16 + rsub;
      int bb = rowg >> 12, n0 = rowg & 4095;
      int bh = bb * 8 + hcol;
      if (part == 0) {  // q: [bh][n][d]
        bf16* dst = qh + ((size_t)bh * 4096 + n0) * 64;
#pragma unroll
        for (int r = 0; r < 4; ++r)
#pragma unroll
          for (int fn = 0; fn < 4; ++fn) {
            float xv = (acc[m][fn][r] - mu[r]) * rs[r] * g4[fn] + b4[fn];
            dst[(size_t)r * 64 + fn * 16 + dlane] = (bf16)xv;
          }
      } else {          // k: LN, store transposed [bh][d][n]
#pragma unroll
        for (int fn = 0; fn < 4; ++fn) {
          bf16x4 pk;
#pragma unroll
          for (int r = 0; r < 4; ++r)
            pk[r] = (bf16)((acc[m][fn][r] - mu[r]) * rs[r] * g4[fn] + b4[fn]);
          *(bf16x4*)(kt + ((size_t)bh * 64 + fn * 16 + dlane) * 4096 + n0) = pk;
        }
      }
    }
  }
}

// ---------------- dots^T = V^T K per (b,h), split-K=8, deterministic partials ----
__global__ __launch_bounds__(64) void k_dots(const bf16* __restrict__ vt,
                                             const bf16* __restrict__ kt,
                                             float* __restrict__ dTp) {
  __shared__ bf16 lA[64 * 64];
  __shared__ bf16 lB[64 * 64];
  const int lane = threadIdx.x;
  const int bh = blockIdx.y, ch = blockIdx.x;
  const bf16* Ab = vt + (size_t)bh * 64 * 4096 + ch * 512;
  const bf16* Bb = kt + (size_t)bh * 64 * 4096 + ch * 512;
  f32x4 acc[4][4] = {};
  const int srow = lane >> 3;
  const int sblk = (lane & 7) ^ srow;
  for (int ktile = 0; ktile < 8; ++ktile) {
    __syncthreads();
#pragma unroll
    for (int i = 0; i < 8; ++i) {
      int row = i * 8 + srow;
      gld_lds16(Ab + (size_t)row * 4096 + ktile * 64 + sblk * 8, (char*)lA + i * 1024);
      gld_lds16(Bb + (size_t)row * 4096 + ktile * 64 + sblk * 8, (char*)lB + i * 1024);
    }
    __syncthreads();
#pragma unroll
    for (int ks = 0; ks < 2; ++ks) {
      bf16x8 af[4], bq[4];
#pragma unroll
      for (int f = 0; f < 4; ++f) {
        int row = f * 16 + (lane & 15);
        int sb = (ks * 4 + (lane >> 4)) ^ (row & 7);
        af[f] = *(const bf16x8*)(lA + row * 64 + sb * 8);
        bq[f] = *(const bf16x8*)(lB + row * 64 + sb * 8);
      }
#pragma unroll
      for (int fm = 0; fm < 4; ++fm)
#pragma unroll
        for (int fn = 0; fn < 4; ++fn)
          acc[fm][fn] = mfma_bf16_16x16x32(af[fm], bq[fn], acc[fm][fn]);
    }
  }
  float* outp = dTp + (size_t)ch * 262144 + (size_t)bh * 4096;
#pragma unroll
  for (int fm = 0; fm < 4; ++fm)
#pragma unroll
    for (int fn = 0; fn < 4; ++fn)
#pragma unroll
      for (int r = 0; r < 4; ++r) {
        int e = fm * 16 + (lane >> 4) * 4 + r;
        int dd = fn * 16 + (lane & 15);
        outp[e * 64 + dd] = acc[fm][fn][r];
      }
}

// ---------------- reduce split-K partials, cast to bf16 ----------------
__global__ __launch_bounds__(256) void k_cvt_dt(const float* __restrict__ dTp,
                                                bf16* __restrict__ dTb) {
  int i = blockIdx.x * 256 + threadIdx.x;
  float s = 0.f;
#pragma unroll
  for (int c = 0; c < 8; ++c) s += dTp[(size_t)c * 262144 + i];
  dTb[i] = (bf16)s;
}

// ---------------- out = (Q @ dots) / n ----------------
__global__ __launch_bounds__(256) void k_out(const bf16* __restrict__ qh,
                                             const bf16* __restrict__ dTb,
                                             float* __restrict__ out) {
  __shared__ bf16 lA[128 * 64];
  const int tid = threadIdx.x, lane = tid & 63, w = tid >> 6;
  const int wm = w >> 1, wn = w & 1;
  const int bh = blockIdx.y, mt = blockIdx.x;
  const int bb = bh >> 3, h = bh & 7;
  const bf16* Ab = qh + (size_t)bh * 4096 * 64 + (size_t)mt * 128 * 64;
  const int srow = lane >> 3, sblk = (lane & 7) ^ srow;
#pragma unroll
  for (int i = 0; i < 4; ++i) {
    int slot = w * 4 + i;
    int row = slot * 8 + srow;
    gld_lds16(Ab + (size_t)row * 64 + sblk * 8, (char*)lA + slot * 1024);
  }
  __syncthreads();
  const bf16* Bb = dTb + (size_t)bh * 4096;
  f32x4 acc[4][2] = {};
#pragma unroll
  for (int ks = 0; ks < 2; ++ks) {
    bf16x8 af[4], bq[2];
#pragma unroll
    for (int f = 0; f < 4; ++f) {
      int row = wm * 64 + f * 16 + (lane & 15);
      int sb = (ks * 4 + (lane >> 4)) ^ (row & 7);
      af[f] = *(const bf16x8*)(lA + row * 64 + sb * 8);
    }
#pragma unroll
    for (int fn = 0; fn < 2; ++fn) {
      int e = wn * 32 + fn * 16 + (lane & 15);
      bq[fn] = *(const bf16x8*)(Bb + e * 64 + ks * 32 + (lane >> 4) * 8);
    }
#pragma unroll
    for (int fm = 0; fm < 4; ++fm)
#pragma unroll
      for (int fn = 0; fn < 2; ++fn)
        acc[fm][fn] = mfma_bf16_16x16x32(af[fm], bq[fn], acc[fm][fn]);
  }
#pragma unroll
  for (int fm = 0; fm < 4; ++fm)
#pragma unroll
    for (int fn = 0; fn < 2; ++fn)
#pragma unroll
      for (int r = 0; r < 4; ++r) {
        int n = mt * 128 + wm * 64 + fm * 16 + (lane >> 4) * 4 + r;
        int e = wn * 32 + fn * 16 + (lane & 15);
        out[((size_t)bb * 4096 + n) * 512 + h * 64 + e] = acc[fm][fn][r] * (1.0f / 4096.0f);
      }
}

extern "C" void kernel_launch(void* const* d_in, const int* in_sizes, int n_in,
                              void* d_out, int out_size, void* d_ws, size_t ws_size,
                              hipStream_t stream) {
  const float* x  = (const float*)d_in[0];
  const float* wq = (const float*)d_in[1];
  const float* qg = (const float*)d_in[2];
  const float* qb = (const float*)d_in[3];
  const float* kg = (const float*)d_in[4];
  const float* kb = (const float*)d_in[5];
  float* out = (float*)d_out;
  char* ws = (char*)d_ws;

  bf16* wT  = (bf16*)(ws);                          // 1.5 MB [1536][512]
  bf16* qh  = (bf16*)(ws + ((size_t)2 << 20));      // 32 MB  [64][4096][64]
  bf16* kt  = (bf16*)(ws + ((size_t)34 << 20));     // 32 MB  [64][64][4096]
  bf16* vt  = (bf16*)(ws + ((size_t)66 << 20));     // 32 MB  [64][64][4096]
  float* dTp = (float*)(ws + ((size_t)98 << 20));   // 8 MB
  bf16* dTb  = (bf16*)(ws + ((size_t)107 << 20));   // 0.5 MB

  k_prep_w<<<3072, 256, 0, stream>>>(wq, wT);
  k_qkv_gemm<<<768, 512, 131072, stream>>>(x, wT, qg, qb, kg, kb, qh, kt, vt);
  k_dots<<<dim3(8, 64), 64, 0, stream>>>(vt, kt, dTp);
  k_cvt_dt<<<1024, 256, 0, stream>>>(dTp, dTb);
  k_out<<<dim3(32, 64), 256, 0, stream>>>(qh, dTb, out);
}

// Round 8
// 112.787 us; speedup vs baseline: 1.5644x; 1.1964x over previous
//
#include <hip/hip_runtime.h>
#include <hip/hip_bf16.h>
#include <stdint.h>

typedef __bf16 bf16;
typedef __bf16 bf16x8 __attribute__((ext_vector_type(8)));
typedef __bf16 bf16x4 __attribute__((ext_vector_type(4)));
typedef float  f32x4  __attribute__((ext_vector_type(4)));
typedef unsigned int u32;

typedef __attribute__((address_space(1))) u32 gu32;
typedef __attribute__((address_space(3))) u32 lu32;

__device__ __forceinline__ void gld_lds16(const void* g, void* l) {
  __builtin_amdgcn_global_load_lds((gu32*)(uintptr_t)g, (lu32*)(u32)(uintptr_t)l, 16, 0, 0);
}

__device__ __forceinline__ f32x4 mfma_bf16_16x16x32(bf16x8 a, bf16x8 b, f32x4 c) {
  return __builtin_amdgcn_mfma_f32_16x16x32_bf16(a, b, c, 0, 0, 0);
}

#define LGKM0 do { asm volatile("s_waitcnt lgkmcnt(0)" ::: "memory"); \
                   __builtin_amdgcn_sched_barrier(0); } while (0)
#define VMC(n) do { asm volatile("s_waitcnt vmcnt(" #n ")" ::: "memory"); } while (0)
#define BAR __builtin_amdgcn_s_barrier()
#define PRIO1 __builtin_amdgcn_s_setprio(1)
#define PRIO0 __builtin_amdgcn_s_setprio(0)

// ---------------- cast x (fp32 -> bf16), 8 elems/thread ----------------
__global__ __launch_bounds__(256) void k_cast_x(const float* __restrict__ x,
                                                bf16* __restrict__ xb) {
  size_t i = (size_t)blockIdx.x * 256 + threadIdx.x;
  const float4* p = (const float4*)x + i * 2;
  float4 a = p[0], b = p[1];
  bf16x8 o;
  o[0] = (bf16)a.x; o[1] = (bf16)a.y; o[2] = (bf16)a.z; o[3] = (bf16)a.w;
  o[4] = (bf16)b.x; o[5] = (bf16)b.y; o[6] = (bf16)b.z; o[7] = (bf16)b.w;
  *(bf16x8*)(xb + i * 8) = o;
}

// -------- transpose + PERMUTE w [512][1536] f32 -> wT [1536][512] bf16 --------
// wT row r: r<512 -> q col r.  r>=512: rr=r-512, hp=rr>>8, q2=(rr>>6)&3, d=r&63,
// h=2*hp+(q2&1); src col = (q2<2 ? 512 : 1024) + h*64 + d.
// So kv tile hp (wT rows 512+hp*256..+255) = [k_{2hp} | k_{2hp+1} | v_{2hp} | v_{2hp+1}].
__global__ __launch_bounds__(256) void k_prep_w(const float* __restrict__ w,
                                                bf16* __restrict__ wT) {
  int idx = blockIdx.x * 256 + threadIdx.x;
  int r = idx >> 9;
  int k = idx & 511;
  int c;
  if (r < 512) {
    c = r;
  } else {
    int rr = r - 512;
    int hp = rr >> 8;
    int q2 = (rr >> 6) & 3;
    int d = r & 63;
    int h = 2 * hp + (q2 & 1);
    c = ((q2 < 2) ? 512 : 1024) + h * 64 + d;
  }
  wT[idx] = (bf16)w[k * 1536 + c];
}

template <int MH, int NH>
__device__ __forceinline__ void mm(f32x4 (&acc)[8][4],
                                   const bf16x8 (&a)[4][2],
                                   const bf16x8 (&b)[2][2]) {
#pragma unroll
  for (int fm = 0; fm < 4; ++fm)
#pragma unroll
    for (int fn = 0; fn < 2; ++fn)
#pragma unroll
      for (int ks = 0; ks < 2; ++ks)
        acc[MH * 4 + fm][NH * 2 + fn] =
            mfma_bf16_16x16x32(a[fm][ks], b[fn][ks], acc[MH * 4 + fm][NH * 2 + fn]);
}

// ---------------- QKV GEMM (R2 main loop) + fused in-LDS dots epilogue ----------
// tn 0,1: q tiles -> LN + store qh [bh][n][d].
// tn 2..5: kv tile for head-pair hp=tn-2 -> k-LN / v to LDS [d][n] (swizzled),
//          then 8 waves compute dots partials D[e][dk] = sum_n v[n][e] k[n][dk]
//          over this block's 256 rows; write f32 partial to dTp[bh][tm&15][.].
__global__ __launch_bounds__(512, 2) void k_qkv_gemm(
    const bf16* __restrict__ A, const bf16* __restrict__ Bt,
    const float* __restrict__ qg, const float* __restrict__ qbeta,
    const float* __restrict__ kg, const float* __restrict__ kbeta,
    bf16* __restrict__ qh, float* __restrict__ dTp)
{
  extern __shared__ bf16 lds[];
  const int tid = threadIdx.x;
  const int lane = tid & 63;
  const int w = tid >> 6;        // 0..7
  const int wm = w >> 2;         // 0..1
  const int wn = w & 3;          // 0..3

  const int wg = blockIdx.x;
  const int swz = (wg & 7) * 96 + (wg >> 3);
  const int tn = swz % 6;
  const int tm = swz / 6;

  auto stA = [&](int buf, int slot, int ktile) {
#pragma unroll
    for (int i = 0; i < 2; ++i) {
      int vr = i * 64 + w * 8 + (lane >> 3);
      int grow = tm * 256 + (vr >> 6) * 128 + slot * 64 + (vr & 63);
      int gk = ktile * 64 + (((lane & 7) ^ (vr & 7)) * 8);
      gld_lds16(A + (size_t)grow * 512 + gk,
                (char*)lds + (buf * 2 + slot) * 16384 + i * 8192 + w * 1024);
    }
  };
  auto stB = [&](int buf, int slot, int ktile) {
#pragma unroll
    for (int i = 0; i < 2; ++i) {
      int vr = i * 64 + w * 8 + (lane >> 3);
      int grow = tn * 256 + (vr >> 5) * 64 + slot * 32 + (vr & 31);
      int gk = ktile * 64 + (((lane & 7) ^ (vr & 7)) * 8);
      gld_lds16(Bt + (size_t)grow * 512 + gk,
                (char*)lds + 65536 + (buf * 2 + slot) * 16384 + i * 8192 + w * 1024);
    }
  };
  auto rdA = [&](int buf, int mh, bf16x8 (&fr)[4][2]) {
    const bf16* base = lds + (buf * 2 + mh) * 8192;
#pragma unroll
    for (int f = 0; f < 4; ++f) {
      int vr = wm * 64 + f * 16 + (lane & 15);
#pragma unroll
      for (int ks = 0; ks < 2; ++ks) {
        int pb = (ks * 4 + (lane >> 4)) ^ (vr & 7);
        fr[f][ks] = *(const bf16x8*)(base + vr * 64 + pb * 8);
      }
    }
  };
  auto rdB = [&](int buf, int nh, bf16x8 (&fr)[2][2]) {
    const bf16* base = lds + 32768 + (buf * 2 + nh) * 8192;
#pragma unroll
    for (int f = 0; f < 2; ++f) {
      int vr = wn * 32 + f * 16 + (lane & 15);
#pragma unroll
      for (int ks = 0; ks < 2; ++ks) {
        int pb = (ks * 4 + (lane >> 4)) ^ (vr & 7);
        fr[f][ks] = *(const bf16x8*)(base + vr * 64 + pb * 8);
      }
    }
  };

  bf16x8 afr[4][2];
  bf16x8 bfr[2][2][2];
  f32x4 acc[8][4];
  {
    f32x4 z = {0.f, 0.f, 0.f, 0.f};
#pragma unroll
    for (int m = 0; m < 8; ++m)
#pragma unroll
      for (int n = 0; n < 4; ++n) acc[m][n] = z;
  }

  // ---- prologue: fully stage tiles 0 and 1 ----
  stA(0, 0, 0); stB(0, 0, 0); stA(0, 1, 0); stB(0, 1, 0);
  stA(1, 0, 1); stB(1, 0, 1); stA(1, 1, 1); stB(1, 1, 1);
  asm volatile("s_waitcnt vmcnt(8)" ::: "memory");
  BAR;

  for (int t = 0; t < 8; ++t) {
    const int d = t & 1;
    rdA(d, 0, afr);
    rdB(d, 0, bfr[0]);
    if (t >= 1 && t <= 6) stA(d ^ 1, 1, t + 1);
    BAR;
    LGKM0;
    PRIO1; mm<0, 0>(acc, afr, bfr[0]); PRIO0;
    BAR;

    rdB(d, 1, bfr[1]);
    if (t >= 1 && t <= 6) stB(d ^ 1, 1, t + 1);
    BAR;
    LGKM0;
    PRIO1; mm<0, 1>(acc, afr, bfr[1]); PRIO0;
    BAR;

    rdA(d, 1, afr);
    if (t <= 5) stA(d, 0, t + 2);
    BAR;
    LGKM0;
    PRIO1; mm<1, 0>(acc, afr, bfr[0]); PRIO0;
    BAR;

    if (t <= 5) stB(d, 0, t + 2);
    BAR;
    PRIO1; mm<1, 1>(acc, afr, bfr[1]); PRIO0;
    if (t < 6) { VMC(4); } else if (t == 6) { VMC(0); }
    BAR;
  }

  const int dlane = lane & 15;
  const int rsub = (lane >> 4) * 4;

  if (tn < 2) {
    // ---- q epilogue: LN + store [bh][n][d] ----
    const int hcol = tn * 4 + wn;    // head 0..7
    float g4[4], b4[4];
#pragma unroll
    for (int fn = 0; fn < 4; ++fn) {
      g4[fn] = qg[fn * 16 + dlane];
      b4[fn] = qbeta[fn * 16 + dlane];
    }
#pragma unroll
    for (int m = 0; m < 8; ++m) {
      float mu[4], rs[4];
#pragma unroll
      for (int r = 0; r < 4; ++r) {
        float s  = acc[m][0][r] + acc[m][1][r] + acc[m][2][r] + acc[m][3][r];
        float s2 = acc[m][0][r] * acc[m][0][r] + acc[m][1][r] * acc[m][1][r]
                 + acc[m][2][r] * acc[m][2][r] + acc[m][3][r] * acc[m][3][r];
#pragma unroll
        for (int msk = 1; msk < 16; msk <<= 1) {
          s  += __shfl_xor(s, msk, 64);
          s2 += __shfl_xor(s2, msk, 64);
        }
        float mean = s * (1.0f / 64.0f);
        float var  = s2 * (1.0f / 64.0f) - mean * mean;
        mu[r] = mean;
        rs[r] = rsqrtf(var + 1e-5f);
      }
      int rowg = tm * 256 + wm * 128 + m * 16 + rsub;
      int bb = rowg >> 12, n0 = rowg & 4095;
      int bh = bb * 8 + hcol;
      bf16* dst = qh + ((size_t)bh * 4096 + n0) * 64;
#pragma unroll
      for (int r = 0; r < 4; ++r)
#pragma unroll
        for (int fn = 0; fn < 4; ++fn) {
          float xv = (acc[m][fn][r] - mu[r]) * rs[r] * g4[fn] + b4[fn];
          dst[(size_t)r * 64 + fn * 16 + dlane] = (bf16)xv;
        }
    }
  } else {
    // ---- kv epilogue: k-LN / v -> LDS [d][n] swizzled; then in-LDS dots ----
    const int hp = tn - 2;
    const bool isK = (wn < 2);
    const int hloc = wn & 1;
    // region: kT h0 @0, kT h1 @32KB, vT h0 @64KB, vT h1 @96KB; row d: 512B, 256 n
    char* reg = (char*)lds + ((isK ? 0 : 2) + hloc) * 32768;
    float g4[4], b4[4];
    if (isK) {
#pragma unroll
      for (int fn = 0; fn < 4; ++fn) {
        g4[fn] = kg[fn * 16 + dlane];
        b4[fn] = kbeta[fn * 16 + dlane];
      }
    }
#pragma unroll
    for (int m = 0; m < 8; ++m) {
      float mu[4] = {}, rs[4] = {};
      if (isK) {
#pragma unroll
        for (int r = 0; r < 4; ++r) {
          float s  = acc[m][0][r] + acc[m][1][r] + acc[m][2][r] + acc[m][3][r];
          float s2 = acc[m][0][r] * acc[m][0][r] + acc[m][1][r] * acc[m][1][r]
                   + acc[m][2][r] * acc[m][2][r] + acc[m][3][r] * acc[m][3][r];
#pragma unroll
          for (int msk = 1; msk < 16; msk <<= 1) {
            s  += __shfl_xor(s, msk, 64);
            s2 += __shfl_xor(s2, msk, 64);
          }
          float mean = s * (1.0f / 64.0f);
          float var  = s2 * (1.0f / 64.0f) - mean * mean;
          mu[r] = mean;
          rs[r] = rsqrtf(var + 1e-5f);
        }
      }
      int n0 = wm * 128 + m * 16 + rsub;          // 0..255 within block
#pragma unroll
      for (int fn = 0; fn < 4; ++fn) {
        int dd = fn * 16 + dlane;
        bf16x4 pk;
#pragma unroll
        for (int r = 0; r < 4; ++r) {
          float xv = isK ? ((acc[m][fn][r] - mu[r]) * rs[r] * g4[fn] + b4[fn])
                         : acc[m][fn][r];
          pk[r] = (bf16)xv;
        }
        int blk = (n0 >> 2) ^ ((dd & 7) << 1);    // 8B granules, XOR swizzle
        *(bf16x4*)(reg + dd * 512 + blk * 8) = pk;
      }
    }
    LGKM0;
    BAR;
    // ---- dots: wave (hsel = w>>2) head 2hp+hsel; qd = w&3 -> e-rows [16qd,16qd+16)
    const int hsel = w >> 2;
    const int qd = w & 3;
    const char* Abase = (char*)lds + (2 + hsel) * 32768;  // vT (e rows)
    const char* Bbase = (char*)lds + hsel * 32768;        // kT (dk rows)
    f32x4 dacc[4] = {};
#pragma unroll
    for (int t8 = 0; t8 < 8; ++t8) {
      int blkb = t8 * 8 + (lane >> 4) * 2;        // n-slice granule base
      int rA = qd * 16 + dlane;
      bf16x8 va = *(const bf16x8*)(Abase + rA * 512 + (blkb ^ ((rA & 7) << 1)) * 8);
#pragma unroll
      for (int j = 0; j < 4; ++j) {
        int rB = j * 16 + dlane;
        bf16x8 vb = *(const bf16x8*)(Bbase + rB * 512 + (blkb ^ ((rB & 7) << 1)) * 8);
        dacc[j] = mfma_bf16_16x16x32(va, vb, dacc[j]);
      }
    }
    int bh = (tm >> 4) * 8 + 2 * hp + hsel;
    float* outp = dTp + ((size_t)bh * 16 + (tm & 15)) * 4096;
#pragma unroll
    for (int j = 0; j < 4; ++j)
#pragma unroll
      for (int r = 0; r < 4; ++r) {
        int e = qd * 16 + (lane >> 4) * 4 + r;
        outp[e * 64 + j * 16 + dlane] = dacc[j][r];
      }
  }
}

// ---------------- reduce 16 dots partials, cast to bf16 ----------------
__global__ __launch_bounds__(256) void k_cvt_dt(const float* __restrict__ dTp,
                                                bf16* __restrict__ dTb) {
  int j = blockIdx.x * 256 + threadIdx.x;   // 262144 = 64 bh * 4096
  int bh = j >> 12;
  int i = j & 4095;
  const float* p = dTp + (size_t)bh * 65536 + i;
  float s = 0.f;
#pragma unroll
  for (int c = 0; c < 16; ++c) s += p[c * 4096];
  dTb[j] = (bf16)s;
}

// ---------------- out = (Q @ dots) / n ----------------
__global__ __launch_bounds__(256) void k_out(const bf16* __restrict__ qh,
                                             const bf16* __restrict__ dTb,
                                             float* __restrict__ out) {
  __shared__ bf16 lA[128 * 64];
  const int tid = threadIdx.x, lane = tid & 63, w = tid >> 6;
  const int wm = w >> 1, wn = w & 1;
  const int bh = blockIdx.y, mt = blockIdx.x;
  const int bb = bh >> 3, h = bh & 7;
  const bf16* Ab = qh + (size_t)bh * 4096 * 64 + (size_t)mt * 128 * 64;
  const int srow = lane >> 3, sblk = (lane & 7) ^ srow;
#pragma unroll
  for (int i = 0; i < 4; ++i) {
    int slot = w * 4 + i;
    int row = slot * 8 + srow;
    gld_lds16(Ab + (size_t)row * 64 + sblk * 8, (char*)lA + slot * 1024);
  }
  __syncthreads();
  const bf16* Bb = dTb + (size_t)bh * 4096;
  f32x4 acc[4][2] = {};
#pragma unroll
  for (int ks = 0; ks < 2; ++ks) {
    bf16x8 af[4], bq[2];
#pragma unroll
    for (int f = 0; f < 4; ++f) {
      int row = wm * 64 + f * 16 + (lane & 15);
      int sb = (ks * 4 + (lane >> 4)) ^ (row & 7);
      af[f] = *(const bf16x8*)(lA + row * 64 + sb * 8);
    }
#pragma unroll
    for (int fn = 0; fn < 2; ++fn) {
      int e = wn * 32 + fn * 16 + (lane & 15);
      bq[fn] = *(const bf16x8*)(Bb + e * 64 + ks * 32 + (lane >> 4) * 8);
    }
#pragma unroll
    for (int fm = 0; fm < 4; ++fm)
#pragma unroll
      for (int fn = 0; fn < 2; ++fn)
        acc[fm][fn] = mfma_bf16_16x16x32(af[fm], bq[fn], acc[fm][fn]);
  }
#pragma unroll
  for (int fm = 0; fm < 4; ++fm)
#pragma unroll
    for (int fn = 0; fn < 2; ++fn)
#pragma unroll
      for (int r = 0; r < 4; ++r) {
        int n = mt * 128 + wm * 64 + fm * 16 + (lane >> 4) * 4 + r;
        int e = wn * 32 + fn * 16 + (lane & 15);
        out[((size_t)bb * 4096 + n) * 512 + h * 64 + e] = acc[fm][fn][r] * (1.0f / 4096.0f);
      }
}

extern "C" void kernel_launch(void* const* d_in, const int* in_sizes, int n_in,
                              void* d_out, int out_size, void* d_ws, size_t ws_size,
                              hipStream_t stream) {
  const float* x  = (const float*)d_in[0];
  const float* wq = (const float*)d_in[1];
  const float* qg = (const float*)d_in[2];
  const float* qb = (const float*)d_in[3];
  const float* kg = (const float*)d_in[4];
  const float* kb = (const float*)d_in[5];
  float* out = (float*)d_out;
  char* ws = (char*)d_ws;

  bf16* xb  = (bf16*)(ws);                          // 32 MB  [32768][512]
  bf16* wT  = (bf16*)(ws + ((size_t)32 << 20));     // 1.5 MB [1536][512] permuted
  bf16* qh  = (bf16*)(ws + ((size_t)34 << 20));     // 32 MB  [64][4096][64]
  float* dTp = (float*)(ws + ((size_t)66 << 20));   // 16.8 MB [64][16][4096]
  bf16* dTb  = (bf16*)(ws + ((size_t)83 << 20));    // 0.5 MB

  k_cast_x<<<8192, 256, 0, stream>>>(x, xb);
  k_prep_w<<<3072, 256, 0, stream>>>(wq, wT);
  k_qkv_gemm<<<768, 512, 131072, stream>>>(xb, wT, qg, qb, kg, kb, qh, dTp);
  k_cvt_dt<<<1024, 256, 0, stream>>>(dTp, dTb);
  k_out<<<dim3(32, 64), 256, 0, stream>>>(qh, dTb, out);
}